// Round 4
// baseline (421.448 us; speedup 1.0000x reference)
//
#include <hip/hip_runtime.h>

// MHA forward, MI355X gfx950. B=4 D=1024 S=2048 H=16 hd=64.
// R10 (resubmit; prior run died to container infra, kernel audited clean:
// no barriers/spin/OOB -> cannot hang). attn drops LDS staging + barriers
// entirely. K/V are L2-resident by XCD pinning (bh%8; 8 heads x 512KB =
// 4MB/XCD) and all 4 waves of a block read IDENTICAL fragments -> L1 serves
// repeats. Fragments load straight from global into VGPRs; waves free-run
// (no syncthreads, no vmcnt(0) drains) so drifted waves overlap MFMA with
// exp/permlane VALU (R8/R9 measured the barrier-locked structure
// alternating pipes: 43+53=96%). P transpose stays in-register
// (permlane32+permlane16). GEMMs unchanged.

typedef __bf16 bf16;
typedef __attribute__((ext_vector_type(8))) __bf16 bf16x8;
typedef __attribute__((ext_vector_type(4))) __bf16 bf16x4;
typedef __attribute__((ext_vector_type(2))) __bf16 bf16x2;
typedef __attribute__((ext_vector_type(4))) float f32x4;
typedef __attribute__((ext_vector_type(2))) unsigned int uintx2;
typedef __attribute__((ext_vector_type(4))) unsigned int uintx4;

#define NB 4
#define ND 1024
#define NS 2048
#define NH 16
#define NM 8192  // NB*NS

__device__ __forceinline__ void gld16(const void* g, void* l) {
  __builtin_amdgcn_global_load_lds((__attribute__((address_space(1))) void*)g,
                                   (__attribute__((address_space(3))) void*)l, 16, 0, 0);
}

__device__ __forceinline__ float exp2_fast(float x) {
#if __has_builtin(__builtin_amdgcn_exp2f)
  return __builtin_amdgcn_exp2f(x);
#else
  return exp2f(x);
#endif
}

__device__ __forceinline__ unsigned pk2(float a, float b) {
  bf16x2 t;
  t[0] = (bf16)a;
  t[1] = (bf16)b;
  return __builtin_bit_cast(unsigned int, t);
}

// Exchange within lane groups {rl, rl+16, rl+32, rl+48}:
// inputs  a = dword of keys {4*quad+0, 4*quad+1} (jk even tile),
//         b = same for jk odd tile (keys 16+4*quad+{0,1}).
// outputs lo = keys {8*quad+0, 8*quad+1}, hi = keys {8*quad+4, 8*quad+5}
// of the 32-key half — i.e. the PV A-operand dword layout.
__device__ __forceinline__ void lane_xchg(unsigned a, unsigned b, unsigned& lo,
                                          unsigned& hi) {
#if __has_builtin(__builtin_amdgcn_permlane32_swap) && \
    __has_builtin(__builtin_amdgcn_permlane16_swap)
  // P = [A_lo32 | B_lo32], Q = [A_hi32 | B_hi32]
  uintx2 r = __builtin_amdgcn_permlane32_swap(a, b, false, false);
  // perfect shuffle of 16-lane rows: lo = [p0 q0 p2 q2], hi = [p1 q1 p3 q3]
  uintx2 r2 = __builtin_amdgcn_permlane16_swap(r[0], r[1], false, false);
  lo = r2[0];
  hi = r2[1];
#else
  const int lane = threadIdx.x & 63;
  const int src = (lane & 15) + ((lane >> 4) & 1) * 32;
  const unsigned as = (unsigned)__shfl((int)a, src, 64);
  const unsigned bs = (unsigned)__shfl((int)b, src, 64);
  const unsigned as2 = (unsigned)__shfl((int)a, src + 16, 64);
  const unsigned bs2 = (unsigned)__shfl((int)b, src + 16, 64);
  lo = (lane >= 32) ? bs : as;
  hi = (lane >= 32) ? bs2 : as2;
#endif
}

// ===================== prep_x: xT[b*S+s][d] = bf16(x[b][d][s] + PE[d][s]) ===
__global__ __launch_bounds__(256) void prep_x_kernel(const float* __restrict__ x,
                                                     bf16* __restrict__ xT) {
  __shared__ float t[32][33];
  const int tx = threadIdx.x, ty = threadIdx.y;
  const int s0 = blockIdx.x * 32, d0 = blockIdx.y * 32, b = blockIdx.z;
#pragma unroll
  for (int i = 0; i < 4; ++i) {
    const int rr = ty + i * 8;
    const int d = d0 + rr, s = s0 + tx;
    const float freq = __expf(-(float)(d >> 1) * 0.01798894603980689f);
    const float ang = (float)s * freq;
    const float pe = (d & 1) ? cosf(ang) : sinf(ang);  // precise: ang up to 2047 rad
    t[rr][tx] = x[((size_t)b * ND + d) * NS + s] + pe;
  }
  __syncthreads();
#pragma unroll
  for (int i = 0; i < 4; ++i) {
    const int a = ty + i * 8;  // s offset
    xT[((size_t)b * NS + s0 + a) * ND + d0 + tx] = (bf16)t[tx][a];
  }
}

// ===================== prep_w: Wq|Wk|Wv -> Wqkv bf16 [3072][1024]; Wo -> bf16
__global__ __launch_bounds__(256) void prep_w_kernel(const float* __restrict__ Wq,
                                                     const float* __restrict__ Wk,
                                                     const float* __restrict__ Wv,
                                                     const float* __restrict__ Wo,
                                                     bf16* __restrict__ Wqkv,
                                                     bf16* __restrict__ WoB) {
  const size_t t = (size_t)blockIdx.x * blockDim.x + threadIdx.x;
  const size_t i = t * 4;
  const float* src;
  bf16* dst;
  size_t off;
  if (i < (size_t)3 * 1024 * 1024) {
    const int sel = (int)(i >> 20);
    src = sel == 0 ? Wq : (sel == 1 ? Wk : Wv);
    off = i - ((size_t)sel << 20);
    dst = Wqkv + i;
  } else {
    src = Wo;
    off = i - ((size_t)3 << 20);
    dst = WoB + off;
  }
  const f32x4 v = *(const f32x4*)(src + off);
  bf16x4 o;
  o[0] = (bf16)v[0];
  o[1] = (bf16)v[1];
  o[2] = (bf16)v[2];
  o[3] = (bf16)v[3];
  *(bf16x4*)dst = o;
}

// ============ shared 128x128 GEMM mainloop, BK=64 (A [M,K], B [N,K], K=1024)
// Tiles 128 rows x 64 cols (16 KB, 128B rows), chunk^(row&7) XOR swizzle.
__device__ __forceinline__ void gemm_tile_128(const bf16* __restrict__ A,
                                              const bf16* __restrict__ Bm,
                                              int tm, int tn, bf16* ldsA, bf16* ldsB,
                                              f32x4 acc[4][4]) {
  const int tid = threadIdx.x;
  const int lane = tid & 63, wave = tid >> 6;
  const int wm = wave >> 1, wn = wave & 1;
  const int rl = lane & 15, quad = lane >> 4;
  int r0[4], c0[4];
#pragma unroll
  for (int j = 0; j < 4; ++j) {
    const int o = (wave * 4 + j) * 1024 + lane * 16;  // byte offset in 16KB tile
    const int r = o >> 7;                             // row (128B rows)
    r0[j] = r;
    c0[j] = ((((o >> 4) & 7) ^ (r & 7)) * 8);  // element col, XOR swizzled
  }
  for (int kt = 0; kt < 1024; kt += 64) {
#pragma unroll
    for (int j = 0; j < 4; ++j) {
      gld16(A + (size_t)(tm + r0[j]) * 1024 + kt + c0[j], (char*)ldsA + (wave * 4 + j) * 1024);
      gld16(Bm + (size_t)(tn + r0[j]) * 1024 + kt + c0[j], (char*)ldsB + (wave * 4 + j) * 1024);
    }
    __syncthreads();
#pragma unroll
    for (int kk = 0; kk < 2; ++kk) {
      bf16x8 af[4], bfr[4];
#pragma unroll
      for (int i = 0; i < 4; ++i) {
        const int ra = wm * 64 + i * 16 + rl;
        af[i] = *(const bf16x8*)((const char*)ldsA + ra * 128 +
                                 (((kk * 4 + quad) ^ (rl & 7)) * 16));
        const int rb = wn * 64 + i * 16 + rl;
        bfr[i] = *(const bf16x8*)((const char*)ldsB + rb * 128 +
                                  (((kk * 4 + quad) ^ (rl & 7)) * 16));
      }
#pragma unroll
      for (int i = 0; i < 4; ++i)
#pragma unroll
        for (int j = 0; j < 4; ++j)
          acc[i][j] =
              __builtin_amdgcn_mfma_f32_16x16x32_bf16(af[i], bfr[j], acc[i][j], 0, 0, 0);
    }
    __syncthreads();
  }
}

// ===================== QKV projection GEMM ==================================
__global__ __launch_bounds__(256, 2) void gemm_qkv_kernel(
    const bf16* __restrict__ xT, const bf16* __restrict__ Wqkv,
    const float* __restrict__ bq, const float* __restrict__ bk,
    const float* __restrict__ bv, bf16* __restrict__ Q, bf16* __restrict__ Kb,
    bf16* __restrict__ VT) {
  __shared__ bf16 ldsA[128 * 64], ldsB[128 * 64];
  const int tm = blockIdx.x * 128, tn = blockIdx.y * 128;
  f32x4 acc[4][4];
  const f32x4 z = {0.f, 0.f, 0.f, 0.f};
#pragma unroll
  for (int i = 0; i < 4; ++i)
#pragma unroll
    for (int j = 0; j < 4; ++j) acc[i][j] = z;
  gemm_tile_128(xT, Wqkv, tm, tn, ldsA, ldsB, acc);
  const int lane = threadIdx.x & 63, wave = threadIdx.x >> 6;
  const int wm = wave >> 1, wn = wave & 1;
  const int rl = lane & 15, quad = lane >> 4;
  // Q scale folds 1/sqrt(64) * log2(e) so attn uses raw 2^x
  const float QSCALE = 0.18033688011112042f;
#pragma unroll
  for (int j = 0; j < 4; ++j) {
    const int n = tn + wn * 64 + j * 16 + rl;  // 0..3071
    const int which = n >> 10;                 // uniform per block
    const int nl = n & 1023;
    const int h = nl >> 6, d = nl & 63;
    const float bias = (which == 0 ? bq : which == 1 ? bk : bv)[nl];
#pragma unroll
    for (int i = 0; i < 4; ++i) {
      const int m0 = tm + wm * 64 + i * 16 + quad * 4;
      const int b = m0 >> 11, s0 = m0 & 2047;
      const size_t bh = (size_t)(b * 16 + h);
      if (which == 2) {
        bf16x4 pk;
#pragma unroll
        for (int r = 0; r < 4; ++r) pk[r] = (bf16)(acc[i][j][r] + bias);
        *(bf16x4*)(VT + ((size_t)bh * 64 + d) * 2048 + s0) = pk;  // V^T packed
      } else {
#pragma unroll
        for (int r = 0; r < 4; ++r) {
          const float v = acc[i][j][r] + bias;
          const int s = s0 + r;
          if (which == 0)
            Q[(bh * 2048 + s) * 64 + d] = (bf16)(v * QSCALE);
          else
            Kb[(bh * 2048 + s) * 64 + d] = (bf16)v;
        }
      }
    }
  }
}

// ===================== flash attention ======================================
// grid (B*H=64, S/128=16): bh%8 = XCD -> each head's K/V pinned to one XCD L2
// (8 heads x 512KB = 4MB/XCD). 128 q/block, 32 q/wave. NO LDS, NO barriers:
// K/V fragments load straight from global (all 4 waves read identical
// addresses -> L1 hits after first toucher). Fragment addressing:
//   K as QK A-operand: row=key (16 rows: jk*16+rl), k-dim=d: lane layout
//     k = quad*8+e -> addr Kb[(bh*2048+key)*64 + quad*8] (+32 for d 32-63).
//   V^T as PV B-operand: row=d (j*16+rl), k-dim=key: addr
//     VT[(bh*64+d)*2048 + kt+ks*32+quad*8].  Both 16B-aligned contiguous.
// V loads issue before the QK->exp->transpose chain that precedes their use
// (~150cy) so L1/L2 latency hides; drifted waves overlap MFMA with VALU.
__global__ __launch_bounds__(256, 4) void attn_kernel(const bf16* __restrict__ Q,
                                                      const bf16* __restrict__ Kb,
                                                      const bf16* __restrict__ VT,
                                                      bf16* __restrict__ AO) {
  const int tid = threadIdx.x;
  const int lane = tid & 63, wave = tid >> 6;
  const int rl = lane & 15, quad = lane >> 4;
  const int bh = blockIdx.x;
  const int q0 = blockIdx.y * 128 + wave * 32;
  const bf16* Qb = Q + ((size_t)bh * 2048 + q0) * 64;
  // per-lane fragment bases
  const bf16* kbase = Kb + ((size_t)bh * 2048 + rl) * 64 + quad * 8;
  const bf16* vbase = VT + ((size_t)bh * 64 + rl) * 2048 + quad * 8;
  // Q fragments (read exactly once; aligned 16B)
  bf16x8 qf[2][2];
#pragma unroll
  for (int i = 0; i < 2; ++i)
#pragma unroll
    for (int ks = 0; ks < 2; ++ks)
      qf[i][ks] = *(const bf16x8*)(Qb + (i * 16 + rl) * 64 + ks * 32 + quad * 8);
  f32x4 o_acc[2][4], lacc[2];  // o_acc[i=q-tile][j=d-tile]
  const f32x4 z = {0.f, 0.f, 0.f, 0.f};
#pragma unroll
  for (int i = 0; i < 2; ++i) {
    lacc[i] = z;
#pragma unroll
    for (int j = 0; j < 4; ++j) o_acc[i][j] = z;
  }
  const bf16 oneb = (bf16)1.0f;
  const bf16x8 onesb = {oneb, oneb, oneb, oneb, oneb, oneb, oneb, oneb};
  for (int kt = 0; kt < 2048; kt += 64) {
#pragma unroll
    for (int ks = 0; ks < 2; ++ks) {
      const int krow = kt + ks * 32;
      // K fragments for the two 16-key tiles of this 32-key half
      const bf16x8 k00 = *(const bf16x8*)(kbase + (size_t)krow * 64);
      const bf16x8 k01 = *(const bf16x8*)(kbase + (size_t)krow * 64 + 32);
      const bf16x8 k10 = *(const bf16x8*)(kbase + (size_t)(krow + 16) * 64);
      const bf16x8 k11 = *(const bf16x8*)(kbase + (size_t)(krow + 16) * 64 + 32);
      // V fragments for this half (used ~150cy later, after QK+exp+permlane)
      bf16x8 vf[4];
#pragma unroll
      for (int j = 0; j < 4; ++j)
        vf[j] = *(const bf16x8*)(vbase + (size_t)(j * 16) * 2048 + krow);
#pragma unroll
      for (int i = 0; i < 2; ++i) {
        __builtin_amdgcn_s_setprio(1);
        f32x4 s0 = __builtin_amdgcn_mfma_f32_16x16x32_bf16(k00, qf[i][0], z, 0, 0, 0);
        s0 = __builtin_amdgcn_mfma_f32_16x16x32_bf16(k01, qf[i][1], s0, 0, 0, 0);
        f32x4 s1 = __builtin_amdgcn_mfma_f32_16x16x32_bf16(k10, qf[i][0], z, 0, 0, 0);
        s1 = __builtin_amdgcn_mfma_f32_16x16x32_bf16(k11, qf[i][1], s1, 0, 0, 0);
        __builtin_amdgcn_s_setprio(0);
        // lane holds P[q=i*16+rl][key jk*16+quad*4+r] -> pack to bf16 dwords
        const unsigned a0 = pk2(exp2_fast(s0[0]), exp2_fast(s0[1]));
        const unsigned a1 = pk2(exp2_fast(s0[2]), exp2_fast(s0[3]));
        const unsigned b0 = pk2(exp2_fast(s1[0]), exp2_fast(s1[1]));
        const unsigned b1 = pk2(exp2_fast(s1[2]), exp2_fast(s1[3]));
        unsigned d0, d1, d2, d3;
        lane_xchg(a0, b0, d0, d2);  // keys 8q+{0,1} and 8q+{4,5}
        lane_xchg(a1, b1, d1, d3);  // keys 8q+{2,3} and 8q+{6,7}
        uintx4 dd;
        dd[0] = d0;
        dd[1] = d1;
        dd[2] = d2;
        dd[3] = d3;
        const bf16x8 pf = __builtin_bit_cast(bf16x8, dd);
        __builtin_amdgcn_s_setprio(1);
        lacc[i] = __builtin_amdgcn_mfma_f32_16x16x32_bf16(pf, onesb, lacc[i], 0, 0, 0);
#pragma unroll
        for (int j = 0; j < 4; ++j)
          o_acc[i][j] =
              __builtin_amdgcn_mfma_f32_16x16x32_bf16(pf, vf[j], o_acc[i][j], 0, 0, 0);
        __builtin_amdgcn_s_setprio(0);
      }
    }
  }
  // lacc rows (quad*4+r) match o_acc rows exactly — per-lane rcp, no shuffles
  const int b = bh >> 4, h = bh & 15;
#pragma unroll
  for (int i = 0; i < 2; ++i) {
    f32x4 linv;
#pragma unroll
    for (int r = 0; r < 4; ++r) linv[r] = __builtin_amdgcn_rcpf(lacc[i][r]);
#pragma unroll
    for (int j = 0; j < 4; ++j)
#pragma unroll
      for (int r = 0; r < 4; ++r) {
        const int s = q0 + i * 16 + quad * 4 + r;
        const int d = h * 64 + j * 16 + rl;
        AO[((size_t)b * 2048 + s) * 1024 + d] = (bf16)(o_acc[i][j][r] * linv[r]);
      }
  }
}

// ===================== output projection GEMM (transposed fp32 store) =======
__global__ __launch_bounds__(256, 2) void gemm_out_kernel(const bf16* __restrict__ AO,
                                                          const bf16* __restrict__ WoB,
                                                          const float* __restrict__ bo,
                                                          float* __restrict__ out) {
  __shared__ bf16 ldsA[128 * 64], ldsB[128 * 64];
  const int tm = blockIdx.x * 128, tn = blockIdx.y * 128;
  f32x4 acc[4][4];
  const f32x4 z = {0.f, 0.f, 0.f, 0.f};
#pragma unroll
  for (int i = 0; i < 4; ++i)
#pragma unroll
    for (int j = 0; j < 4; ++j) acc[i][j] = z;
  gemm_tile_128(AO, WoB, tm, tn, ldsA, ldsB, acc);
  const int lane = threadIdx.x & 63, wave = threadIdx.x >> 6;
  const int wm = wave >> 1, wn = wave & 1;
  const int rl = lane & 15, quad = lane >> 4;
#pragma unroll
  for (int j = 0; j < 4; ++j) {
    const int n = tn + wn * 64 + j * 16 + rl;  // = d
    const float bias = bo[n];
#pragma unroll
    for (int i = 0; i < 4; ++i) {
      const int m0 = tm + wm * 64 + i * 16 + quad * 4;
      const int b = m0 >> 11, s = m0 & 2047;
      f32x4 v = acc[i][j];
      v[0] += bias;
      v[1] += bias;
      v[2] += bias;
      v[3] += bias;
      *(f32x4*)(out + ((size_t)(b * 1024 + n)) * 2048 + s) = v;
    }
  }
}

extern "C" void kernel_launch(void* const* d_in, const int* in_sizes, int n_in,
                              void* d_out, int out_size, void* d_ws, size_t ws_size,
                              hipStream_t stream) {
  const float* x = (const float*)d_in[0];
  const float* Wq = (const float*)d_in[1];
  const float* bq = (const float*)d_in[2];
  const float* Wk = (const float*)d_in[3];
  const float* bk = (const float*)d_in[4];
  const float* Wv = (const float*)d_in[5];
  const float* bv = (const float*)d_in[6];
  const float* Wo = (const float*)d_in[7];
  const float* bo = (const float*)d_in[8];
  float* out = (float*)d_out;

  char* p = (char*)d_ws;
  bf16* xT = (bf16*)p;
  p += (size_t)NM * ND * 2;  // 16 MiB
  bf16* Wqkv = (bf16*)p;
  p += (size_t)3 * ND * ND * 2;  // 6 MiB
  bf16* WoB = (bf16*)p;
  p += (size_t)ND * ND * 2;  // 2 MiB
  bf16* Qb = (bf16*)p;
  p += (size_t)NM * ND * 2;
  bf16* Kbf = (bf16*)p;
  p += (size_t)NM * ND * 2;
  bf16* VTb = (bf16*)p;
  p += (size_t)NM * ND * 2;
  bf16* AO = xT;  // alias: xT fully consumed by gemm_qkv before attn writes AO

  prep_x_kernel<<<dim3(NS / 32, ND / 32, NB), dim3(32, 8), 0, stream>>>(x, xT);
  prep_w_kernel<<<dim3(4096), dim3(256), 0, stream>>>(Wq, Wk, Wv, Wo, Wqkv, WoB);
  gemm_qkv_kernel<<<dim3(NM / 128, 3072 / 128), dim3(256), 0, stream>>>(
      xT, Wqkv, bq, bk, bv, Qb, Kbf, VTb);
  attn_kernel<<<dim3(NB * NH, NS / 128), dim3(256), 0, stream>>>(Qb, Kbf, VTb, AO);
  gemm_out_kernel<<<dim3(NM / 128, ND / 128), dim3(256), 0, stream>>>(AO, WoB, bo, out);
}

// Round 5
// 256.931 us; speedup vs baseline: 1.6403x; 1.6403x over previous
//
#include <hip/hip_runtime.h>

// MHA forward, MI355X gfx950. B=4 D=1024 S=2048 H=16 hd=64.
// R11: revert R10 (global-direct attn was VMEM-latency-bound: Mfma 12.8%).
// Back to R9's LDS-staged structure + IN-WAVE software pipeline: carry raw
// S of half1 across tiles so exppack(t-1,h1) interleaves with QK(t,h0), and
// exppack(t,h0) interleaves with {PV(t-1,h1) + QK(t,h1)} — independent
// chains, pinned with sched_group_barrier. All s_setprio removed (fences
// the scheduler, which is why R8/R9 alternated pipes: 43+53=96%).
// Second barrier per tile protects old-buffer V reads before prefetch.

typedef __bf16 bf16;
typedef __attribute__((ext_vector_type(8))) __bf16 bf16x8;
typedef __attribute__((ext_vector_type(4))) __bf16 bf16x4;
typedef __attribute__((ext_vector_type(2))) __bf16 bf16x2;
typedef __attribute__((ext_vector_type(4))) float f32x4;
typedef __attribute__((ext_vector_type(2))) unsigned int uintx2;
typedef __attribute__((ext_vector_type(4))) unsigned int uintx4;

#define NB 4
#define ND 1024
#define NS 2048
#define NH 16
#define NM 8192  // NB*NS

__device__ __forceinline__ void gld16(const void* g, void* l) {
  __builtin_amdgcn_global_load_lds((__attribute__((address_space(1))) void*)g,
                                   (__attribute__((address_space(3))) void*)l, 16, 0, 0);
}

__device__ __forceinline__ float exp2_fast(float x) {
#if __has_builtin(__builtin_amdgcn_exp2f)
  return __builtin_amdgcn_exp2f(x);
#else
  return exp2f(x);
#endif
}

__device__ __forceinline__ unsigned pk2(float a, float b) {
  bf16x2 t;
  t[0] = (bf16)a;
  t[1] = (bf16)b;
  return __builtin_bit_cast(unsigned int, t);
}

// Exchange within lane groups {rl, rl+16, rl+32, rl+48}: perfect shuffle of
// the swapped-QK^T C-layout dwords into the PV A-operand dword layout.
__device__ __forceinline__ void lane_xchg(unsigned a, unsigned b, unsigned& lo,
                                          unsigned& hi) {
#if __has_builtin(__builtin_amdgcn_permlane32_swap) && \
    __has_builtin(__builtin_amdgcn_permlane16_swap)
  uintx2 r = __builtin_amdgcn_permlane32_swap(a, b, false, false);
  uintx2 r2 = __builtin_amdgcn_permlane16_swap(r[0], r[1], false, false);
  lo = r2[0];
  hi = r2[1];
#else
  const int lane = threadIdx.x & 63;
  const int src = (lane & 15) + ((lane >> 4) & 1) * 32;
  const unsigned as = (unsigned)__shfl((int)a, src, 64);
  const unsigned bs = (unsigned)__shfl((int)b, src, 64);
  const unsigned as2 = (unsigned)__shfl((int)a, src + 16, 64);
  const unsigned bs2 = (unsigned)__shfl((int)b, src + 16, 64);
  lo = (lane >= 32) ? bs : as;
  hi = (lane >= 32) ? bs2 : as2;
#endif
}

// ===================== prep_x: xT[b*S+s][d] = bf16(x[b][d][s] + PE[d][s]) ===
__global__ __launch_bounds__(256) void prep_x_kernel(const float* __restrict__ x,
                                                     bf16* __restrict__ xT) {
  __shared__ float t[32][33];
  const int tx = threadIdx.x, ty = threadIdx.y;
  const int s0 = blockIdx.x * 32, d0 = blockIdx.y * 32, b = blockIdx.z;
#pragma unroll
  for (int i = 0; i < 4; ++i) {
    const int rr = ty + i * 8;
    const int d = d0 + rr, s = s0 + tx;
    const float freq = __expf(-(float)(d >> 1) * 0.01798894603980689f);
    const float ang = (float)s * freq;
    const float pe = (d & 1) ? cosf(ang) : sinf(ang);  // precise: ang up to 2047 rad
    t[rr][tx] = x[((size_t)b * ND + d) * NS + s] + pe;
  }
  __syncthreads();
#pragma unroll
  for (int i = 0; i < 4; ++i) {
    const int a = ty + i * 8;  // s offset
    xT[((size_t)b * NS + s0 + a) * ND + d0 + tx] = (bf16)t[tx][a];
  }
}

// ===================== prep_w: Wq|Wk|Wv -> Wqkv bf16 [3072][1024]; Wo -> bf16
__global__ __launch_bounds__(256) void prep_w_kernel(const float* __restrict__ Wq,
                                                     const float* __restrict__ Wk,
                                                     const float* __restrict__ Wv,
                                                     const float* __restrict__ Wo,
                                                     bf16* __restrict__ Wqkv,
                                                     bf16* __restrict__ WoB) {
  const size_t t = (size_t)blockIdx.x * blockDim.x + threadIdx.x;
  const size_t i = t * 4;
  const float* src;
  bf16* dst;
  size_t off;
  if (i < (size_t)3 * 1024 * 1024) {
    const int sel = (int)(i >> 20);
    src = sel == 0 ? Wq : (sel == 1 ? Wk : Wv);
    off = i - ((size_t)sel << 20);
    dst = Wqkv + i;
  } else {
    src = Wo;
    off = i - ((size_t)3 << 20);
    dst = WoB + off;
  }
  const f32x4 v = *(const f32x4*)(src + off);
  bf16x4 o;
  o[0] = (bf16)v[0];
  o[1] = (bf16)v[1];
  o[2] = (bf16)v[2];
  o[3] = (bf16)v[3];
  *(bf16x4*)dst = o;
}

// ============ shared 128x128 GEMM mainloop, BK=64 (A [M,K], B [N,K], K=1024)
__device__ __forceinline__ void gemm_tile_128(const bf16* __restrict__ A,
                                              const bf16* __restrict__ Bm,
                                              int tm, int tn, bf16* ldsA, bf16* ldsB,
                                              f32x4 acc[4][4]) {
  const int tid = threadIdx.x;
  const int lane = tid & 63, wave = tid >> 6;
  const int wm = wave >> 1, wn = wave & 1;
  const int rl = lane & 15, quad = lane >> 4;
  int r0[4], c0[4];
#pragma unroll
  for (int j = 0; j < 4; ++j) {
    const int o = (wave * 4 + j) * 1024 + lane * 16;  // byte offset in 16KB tile
    const int r = o >> 7;                             // row (128B rows)
    r0[j] = r;
    c0[j] = ((((o >> 4) & 7) ^ (r & 7)) * 8);  // element col, XOR swizzled
  }
  for (int kt = 0; kt < 1024; kt += 64) {
#pragma unroll
    for (int j = 0; j < 4; ++j) {
      gld16(A + (size_t)(tm + r0[j]) * 1024 + kt + c0[j], (char*)ldsA + (wave * 4 + j) * 1024);
      gld16(Bm + (size_t)(tn + r0[j]) * 1024 + kt + c0[j], (char*)ldsB + (wave * 4 + j) * 1024);
    }
    __syncthreads();
#pragma unroll
    for (int kk = 0; kk < 2; ++kk) {
      bf16x8 af[4], bfr[4];
#pragma unroll
      for (int i = 0; i < 4; ++i) {
        const int ra = wm * 64 + i * 16 + rl;
        af[i] = *(const bf16x8*)((const char*)ldsA + ra * 128 +
                                 (((kk * 4 + quad) ^ (rl & 7)) * 16));
        const int rb = wn * 64 + i * 16 + rl;
        bfr[i] = *(const bf16x8*)((const char*)ldsB + rb * 128 +
                                  (((kk * 4 + quad) ^ (rl & 7)) * 16));
      }
#pragma unroll
      for (int i = 0; i < 4; ++i)
#pragma unroll
        for (int j = 0; j < 4; ++j)
          acc[i][j] =
              __builtin_amdgcn_mfma_f32_16x16x32_bf16(af[i], bfr[j], acc[i][j], 0, 0, 0);
    }
    __syncthreads();
  }
}

// ===================== QKV projection GEMM ==================================
__global__ __launch_bounds__(256, 2) void gemm_qkv_kernel(
    const bf16* __restrict__ xT, const bf16* __restrict__ Wqkv,
    const float* __restrict__ bq, const float* __restrict__ bk,
    const float* __restrict__ bv, bf16* __restrict__ Q, bf16* __restrict__ Kb,
    bf16* __restrict__ VT) {
  __shared__ bf16 ldsA[128 * 64], ldsB[128 * 64];
  const int tm = blockIdx.x * 128, tn = blockIdx.y * 128;
  f32x4 acc[4][4];
  const f32x4 z = {0.f, 0.f, 0.f, 0.f};
#pragma unroll
  for (int i = 0; i < 4; ++i)
#pragma unroll
    for (int j = 0; j < 4; ++j) acc[i][j] = z;
  gemm_tile_128(xT, Wqkv, tm, tn, ldsA, ldsB, acc);
  const int lane = threadIdx.x & 63, wave = threadIdx.x >> 6;
  const int wm = wave >> 1, wn = wave & 1;
  const int rl = lane & 15, quad = lane >> 4;
  // Q scale folds 1/sqrt(64) * log2(e) so attn uses raw 2^x
  const float QSCALE = 0.18033688011112042f;
#pragma unroll
  for (int j = 0; j < 4; ++j) {
    const int n = tn + wn * 64 + j * 16 + rl;  // 0..3071
    const int which = n >> 10;                 // uniform per block
    const int nl = n & 1023;
    const int h = nl >> 6, d = nl & 63;
    const float bias = (which == 0 ? bq : which == 1 ? bk : bv)[nl];
#pragma unroll
    for (int i = 0; i < 4; ++i) {
      const int m0 = tm + wm * 64 + i * 16 + quad * 4;
      const int b = m0 >> 11, s0 = m0 & 2047;
      const size_t bh = (size_t)(b * 16 + h);
      if (which == 2) {
        bf16x4 pk;
#pragma unroll
        for (int r = 0; r < 4; ++r) pk[r] = (bf16)(acc[i][j][r] + bias);
        *(bf16x4*)(VT + ((size_t)bh * 64 + d) * 2048 + s0) = pk;  // V^T packed
      } else {
#pragma unroll
        for (int r = 0; r < 4; ++r) {
          const float v = acc[i][j][r] + bias;
          const int s = s0 + r;
          if (which == 0)
            Q[(bh * 2048 + s) * 64 + d] = (bf16)(v * QSCALE);
          else
            Kb[(bh * 2048 + s) * 64 + d] = (bf16)v;
        }
      }
    }
  }
}

// ===================== flash attention ======================================
// grid (B*H=64, S/128=16): bh%8 = XCD pinning. 128 q/block, 32 q/wave.
// LDS-staged K/V (2x8KB dbuf each); in-wave software pipeline: exppack of
// the previous half overlaps the next half's QK/PV MFMAs (independent
// chains, sched_group_barrier-pinned). No setprio (scheduler fence).
__global__ __launch_bounds__(256, 3) void attn_kernel(const bf16* __restrict__ Q,
                                                      const bf16* __restrict__ Kb,
                                                      const bf16* __restrict__ VT,
                                                      bf16* __restrict__ AO) {
  __shared__ __align__(16) char smem[32768];
  char* ldsK = smem;          // 2 x 8 KB (double buffer)
  char* ldsV = smem + 16384;  // 2 x 8 KB (double buffer)
  const int tid = threadIdx.x;
  const int lane = tid & 63, wave = tid >> 6;
  const int rl = lane & 15, quad = lane >> 4;
  const int bh = blockIdx.x;
  const int q0 = blockIdx.y * 128;
  const bf16* Qb = Q + ((size_t)bh * 2048 + q0) * 64;
  const bf16* Kbb = Kb + (size_t)bh * 2048 * 64;
  const bf16* Vb = VT + (size_t)bh * 64 * 2048;
  // staging geometry: 2 x 16B chunks per thread per 8KB tile, rows 128B
  const int o0 = wave * 1024 + lane * 16, o1 = o0 + 4096;
  const int ra = o0 >> 7, rb = o1 >> 7;
  const int ca = (((o0 >> 4) & 7) ^ (ra & 7)) * 16;
  const int cb = (((o1 >> 4) & 7) ^ (rb & 7)) * 16;
  auto stage = [&](int tn, int nb) {  // tile tn -> buffer half nb (bytes)
    gld16((const char*)Kbb + (size_t)(tn * 64 + ra) * 128 + ca, ldsK + nb + wave * 1024);
    gld16((const char*)Kbb + (size_t)(tn * 64 + rb) * 128 + cb,
          ldsK + nb + wave * 1024 + 4096);
    gld16((const char*)Vb + (size_t)ra * 4096 + tn * 128 + ca, ldsV + nb + wave * 1024);
    gld16((const char*)Vb + (size_t)rb * 4096 + tn * 128 + cb,
          ldsV + nb + wave * 1024 + 4096);
  };
  stage(0, 0);  // tile 0 -> buf0
  // Q fragments straight from global (read exactly once; aligned 16B)
  bf16x8 qf[2][2];
#pragma unroll
  for (int i = 0; i < 2; ++i)
#pragma unroll
    for (int ks = 0; ks < 2; ++ks)
      qf[i][ks] =
          *(const bf16x8*)(Qb + (wave * 32 + i * 16 + rl) * 64 + ks * 32 + quad * 8);
  f32x4 o_acc[2][4], lacc[2];
  const f32x4 z = {0.f, 0.f, 0.f, 0.f};
#pragma unroll
  for (int i = 0; i < 2; ++i) {
    lacc[i] = z;
#pragma unroll
    for (int j = 0; j < 4; ++j) o_acc[i][j] = z;
  }
  const bf16 oneb = (bf16)1.0f;
  const bf16x8 onesb = {oneb, oneb, oneb, oneb, oneb, oneb, oneb, oneb};
  const int xa = (quad ^ (rl & 7)) * 16;        // K chunk quad (d 0..31)
  const int xb = ((4 + quad) ^ (rl & 7)) * 16;  // K chunk 4+quad (d 32..63)
  // ---- helpers ----
  auto qk_half = [&](const char* Kbase, int h, f32x4(&s)[2][2]) {
    const int r0o = (h * 32 + rl) * 128, r1o = (h * 32 + 16 + rl) * 128;
    const bf16x8 k00 = *(const bf16x8*)(Kbase + r0o + xa);
    const bf16x8 k01 = *(const bf16x8*)(Kbase + r0o + xb);
    const bf16x8 k10 = *(const bf16x8*)(Kbase + r1o + xa);
    const bf16x8 k11 = *(const bf16x8*)(Kbase + r1o + xb);
#pragma unroll
    for (int i = 0; i < 2; ++i) {
      s[i][0] = __builtin_amdgcn_mfma_f32_16x16x32_bf16(k00, qf[i][0], z, 0, 0, 0);
      s[i][0] = __builtin_amdgcn_mfma_f32_16x16x32_bf16(k01, qf[i][1], s[i][0], 0, 0, 0);
      s[i][1] = __builtin_amdgcn_mfma_f32_16x16x32_bf16(k10, qf[i][0], z, 0, 0, 0);
      s[i][1] = __builtin_amdgcn_mfma_f32_16x16x32_bf16(k11, qf[i][1], s[i][1], 0, 0, 0);
    }
  };
  auto exppack = [&](const f32x4(&s)[2][2], bf16x8(&pf)[2]) {
#pragma unroll
    for (int i = 0; i < 2; ++i) {
      const unsigned a0 = pk2(exp2_fast(s[i][0][0]), exp2_fast(s[i][0][1]));
      const unsigned a1 = pk2(exp2_fast(s[i][0][2]), exp2_fast(s[i][0][3]));
      const unsigned b0 = pk2(exp2_fast(s[i][1][0]), exp2_fast(s[i][1][1]));
      const unsigned b1 = pk2(exp2_fast(s[i][1][2]), exp2_fast(s[i][1][3]));
      unsigned d0, d1, d2, d3;
      lane_xchg(a0, b0, d0, d2);
      lane_xchg(a1, b1, d1, d3);
      uintx4 dd;
      dd[0] = d0;
      dd[1] = d1;
      dd[2] = d2;
      dd[3] = d3;
      pf[i] = __builtin_bit_cast(bf16x8, dd);
    }
  };
  auto ldv = [&](const char* Vbase, int h, bf16x8(&vf)[4]) {
    const int vc = ((h * 4 + quad) ^ (rl & 7)) * 16;
#pragma unroll
    for (int j = 0; j < 4; ++j)
      vf[j] = *(const bf16x8*)(Vbase + (j * 16 + rl) * 128 + vc);
  };
  auto pv = [&](const bf16x8(&pf)[2], const bf16x8(&vf)[4]) {
#pragma unroll
    for (int i = 0; i < 2; ++i)
      lacc[i] = __builtin_amdgcn_mfma_f32_16x16x32_bf16(pf[i], onesb, lacc[i], 0, 0, 0);
#pragma unroll
    for (int j = 0; j < 4; ++j)
#pragma unroll
      for (int i = 0; i < 2; ++i)
        o_acc[i][j] =
            __builtin_amdgcn_mfma_f32_16x16x32_bf16(pf[i], vf[j], o_acc[i][j], 0, 0, 0);
  };
  // ---- pipeline ----
  f32x4 sh0[2][2], sh1[2][2];
  bf16x8 pf0[2], pf1[2], vf0[4], vf1[4];
  __syncthreads();  // tile0 landed
  stage(1, 8192);   // prefetch tile1 -> buf1 (buf1 has no readers yet)
  // t=0 peel (serial; no pipeline partner yet)
  qk_half(ldsK, 0, sh0);
  exppack(sh0, pf0);
  ldv(ldsV, 0, vf0);
  pv(pf0, vf0);
  qk_half(ldsK, 1, sh1);  // raw S of (0,h1) carried into the loop
  for (int t = 1; t < 32; ++t) {
    const char* KbT = ldsK + (t & 1) * 8192;
    const char* VbT = ldsV + (t & 1) * 8192;
    const char* VbO = ldsV + ((t & 1) ^ 1) * 8192;
    __syncthreads();      // tile t landed (prefetch from t-1 drained)
    ldv(VbO, 1, vf1);     // old tile's h1 V -> regs (before buffer reuse)
    // ph1: QK(t,h0) MFMA  ||  exppack(t-1,h1) VALU — independent chains
    qk_half(KbT, 0, sh0);
    exppack(sh1, pf1);
#pragma unroll
    for (int g = 0; g < 8; ++g) {
      __builtin_amdgcn_sched_group_barrier(0x008, 1, 0);  // 1 MFMA
      __builtin_amdgcn_sched_group_barrier(0x002, 5, 0);  // 5 VALU
    }
    if (t < 31) {
      __syncthreads();  // all waves done reading VbO; safe to overwrite
      stage(t + 1, ((t & 1) ^ 1) * 8192);
    }
    // ph2+3: {PV(t-1,h1) + QK(t,h1)} MFMA  ||  exppack(t,h0) VALU
    pv(pf1, vf1);
    qk_half(KbT, 1, sh1);
    exppack(sh0, pf0);
#pragma unroll
    for (int g = 0; g < 18; ++g) {
      __builtin_amdgcn_sched_group_barrier(0x008, 1, 0);  // 1 MFMA
      __builtin_amdgcn_sched_group_barrier(0x002, 2, 0);  // 2 VALU
    }
    // ph4: PV(t,h0)
    ldv(VbT, 0, vf0);
    pv(pf0, vf0);
  }
  // epilogue: tile31 h1 (buf1 intact: staged at t=30, no later overwrite)
  exppack(sh1, pf1);
  ldv(ldsV + 8192, 1, vf1);
  pv(pf1, vf1);
  // lacc rows (quad*4+r) match o_acc rows exactly — per-lane rcp, no shuffles
  const int b = bh >> 4, h = bh & 15;
#pragma unroll
  for (int i = 0; i < 2; ++i) {
    f32x4 linv;
#pragma unroll
    for (int r = 0; r < 4; ++r) linv[r] = __builtin_amdgcn_rcpf(lacc[i][r]);
#pragma unroll
    for (int j = 0; j < 4; ++j)
#pragma unroll
      for (int r = 0; r < 4; ++r) {
        const int s = q0 + wave * 32 + i * 16 + quad * 4 + r;
        const int d = h * 64 + j * 16 + rl;
        AO[((size_t)b * 2048 + s) * 1024 + d] = (bf16)(o_acc[i][j][r] * linv[r]);
      }
  }
}

// ===================== output projection GEMM (transposed fp32 store) =======
__global__ __launch_bounds__(256, 2) void gemm_out_kernel(const bf16* __restrict__ AO,
                                                          const bf16* __restrict__ WoB,
                                                          const float* __restrict__ bo,
                                                          float* __restrict__ out) {
  __shared__ bf16 ldsA[128 * 64], ldsB[128 * 64];
  const int tm = blockIdx.x * 128, tn = blockIdx.y * 128;
  f32x4 acc[4][4];
  const f32x4 z = {0.f, 0.f, 0.f, 0.f};
#pragma unroll
  for (int i = 0; i < 4; ++i)
#pragma unroll
    for (int j = 0; j < 4; ++j) acc[i][j] = z;
  gemm_tile_128(AO, WoB, tm, tn, ldsA, ldsB, acc);
  const int lane = threadIdx.x & 63, wave = threadIdx.x >> 6;
  const int wm = wave >> 1, wn = wave & 1;
  const int rl = lane & 15, quad = lane >> 4;
#pragma unroll
  for (int j = 0; j < 4; ++j) {
    const int n = tn + wn * 64 + j * 16 + rl;  // = d
    const float bias = bo[n];
#pragma unroll
    for (int i = 0; i < 4; ++i) {
      const int m0 = tm + wm * 64 + i * 16 + quad * 4;
      const int b = m0 >> 11, s = m0 & 2047;
      f32x4 v = acc[i][j];
      v[0] += bias;
      v[1] += bias;
      v[2] += bias;
      v[3] += bias;
      *(f32x4*)(out + ((size_t)(b * 1024 + n)) * 2048 + s) = v;
    }
  }
}

extern "C" void kernel_launch(void* const* d_in, const int* in_sizes, int n_in,
                              void* d_out, int out_size, void* d_ws, size_t ws_size,
                              hipStream_t stream) {
  const float* x = (const float*)d_in[0];
  const float* Wq = (const float*)d_in[1];
  const float* bq = (const float*)d_in[2];
  const float* Wk = (const float*)d_in[3];
  const float* bk = (const float*)d_in[4];
  const float* Wv = (const float*)d_in[5];
  const float* bv = (const float*)d_in[6];
  const float* Wo = (const float*)d_in[7];
  const float* bo = (const float*)d_in[8];
  float* out = (float*)d_out;

  char* p = (char*)d_ws;
  bf16* xT = (bf16*)p;
  p += (size_t)NM * ND * 2;  // 16 MiB
  bf16* Wqkv = (bf16*)p;
  p += (size_t)3 * ND * ND * 2;  // 6 MiB
  bf16* WoB = (bf16*)p;
  p += (size_t)ND * ND * 2;  // 2 MiB
  bf16* Qb = (bf16*)p;
  p += (size_t)NM * ND * 2;
  bf16* Kbf = (bf16*)p;
  p += (size_t)NM * ND * 2;
  bf16* VTb = (bf16*)p;
  p += (size_t)NM * ND * 2;
  bf16* AO = xT;  // alias: xT fully consumed by gemm_qkv before attn writes AO

  prep_x_kernel<<<dim3(NS / 32, ND / 32, NB), dim3(32, 8), 0, stream>>>(x, xT);
  prep_w_kernel<<<dim3(4096), dim3(256), 0, stream>>>(Wq, Wk, Wv, Wo, Wqkv, WoB);
  gemm_qkv_kernel<<<dim3(NM / 128, 3072 / 128), dim3(256), 0, stream>>>(
      xT, Wqkv, bq, bk, bv, Qb, Kbf, VTb);
  attn_kernel<<<dim3(NB * NH, NS / 128), dim3(256), 0, stream>>>(Qb, Kbf, VTb, AO);
  gemm_out_kernel<<<dim3(NM / 128, ND / 128), dim3(256), 0, stream>>>(AO, WoB, bo, out);
}